// Round 11
// baseline (94.448 us; speedup 1.0000x reference)
//
#include <hip/hip_runtime.h>
#include <math.h>

#define NB   32
#define NA   64
#define EDIM 256
#define HIS  50
#define DKA  9
#define NV   8

typedef _Float16 HALF;
typedef _Float16 half4 __attribute__((ext_vector_type(4)));
typedef _Float16 half8 __attribute__((ext_vector_type(8)));
typedef float    f32x4 __attribute__((ext_vector_type(4)));

// ws layout (bytes):
#define WS_WKP   0          // f16 B-frag-packed Wk                  131072
#define WS_WVP   131072     // f16 B-frag-packed Wv                  131072
#define WS_WQP   262144     // f16 B-frag-packed Wq                  131072
#define WS_WOP   393216     // f16 B-frag-packed Wout                131072
#define WS_PEH   524288     // f16 PE [50][256]                      25600
#define WS_WET   549888     // f16 WencT A-frags [me=16][lane][8]    16384
#define WS_IDX   566272     // int idxTab [64][50]                   12800
#define WS_QH    579072     // f16 [2048][256]: qh, then overwritten by O (per-row, safe)
#define WS_NEED  1627648ULL

// Branchless exact-GELU: erf via Abramowitz-Stegun 7.1.26 (|err| <= 1.5e-7)
__device__ __forceinline__ float gelu_exact(float x) {
    const float ax = fabsf(x) * 0.70710678118654752f;
    const float t  = __builtin_amdgcn_rcpf(1.0f + 0.3275911f * ax);
    const float p  = t * (0.254829592f + t * (-0.284496736f + t * (1.421413741f
                   + t * (-1.453152027f + t * 1.061405429f))));
    const float er = 1.0f - p * __expf(-ax * ax);
    return 0.5f * x * (1.0f + copysignf(er, x));
}

// ---------------- setup: pack weights (B-frag order), WencT A-frags, PE f16, adjacency ----------------
__global__ __launch_bounds__(256) void pack_setup(
    const float* __restrict__ Wk, const float* __restrict__ Wv,
    const float* __restrict__ Wq, const float* __restrict__ Wout,
    const float* __restrict__ adjs, const float* __restrict__ Wenc,
    char* __restrict__ ws)
{
    const int tid = blockIdx.x * 256 + threadIdx.x;   // 0..65535
    HALF* WkP  = (HALF*)(ws + WS_WKP);
    HALF* WvP  = (HALF*)(ws + WS_WVP);
    HALF* WqP  = (HALF*)(ws + WS_WQP);
    HALF* WoP  = (HALF*)(ws + WS_WOP);
    HALF* PEH  = (HALF*)(ws + WS_PEH);
    HALF* WET  = (HALF*)(ws + WS_WET);
    int*  idxT = (int*)(ws + WS_IDX);

    // B-fragment pack: out = ((ntile*8 + ktile)*64 + lane)*8 + elem
    {
        const int elem = tid & 7;
        const int lane = (tid >> 3) & 63;
        const int kt   = (tid >> 9) & 7;
        const int nt   = tid >> 12;
        const int k = kt * 32 + (lane >> 4) * 8 + elem;
        const int n = nt * 16 + (lane & 15);
        WkP[tid] = (HALF)Wk[k * EDIM + n];
        WvP[tid] = (HALF)Wv[k * EDIM + n];
        WqP[tid] = (HALF)Wq[k * EDIM + n];
        WoP[tid] = (HALF)Wout[k * EDIM + n];
    }
    // PE table, f16
    if (tid < HIS * EDIM) {
        const int t = tid >> 8;
        const int e = tid & 255;
        const float dt = expf(-(float)(e & ~1) * (9.210340371976184f / 256.0f));
        const float arg = (float)t * dt;
        PEH[tid] = (HALF)((e & 1) ? cosf(arg) : sinf(arg));
    }
    // WencT A-frags: WET[(me*64 + lane)*8 + j] = Wenc[k][e], k=(lane>>4)*8+j, e=me*16+(lane&15)
    if (tid < 16 * 64 * 8) {
        const int j    = tid & 7;
        const int lane = (tid >> 3) & 63;
        const int me   = tid >> 9;
        const int k = (lane >> 4) * 8 + j;
        const int e = me * 16 + (lane & 15);
        WET[tid] = (k < DKA) ? (HALF)Wenc[k * EDIM + e] : (HALF)0.0f;
    }
    // adjacency one-hot -> index
    if (tid < NA * HIS) {
        const float* row = adjs + tid * NA;   // tid = n*HIS + t
        int best = 0;
        #pragma unroll
        for (int a = 0; a < NA; ++a) best = (row[a] > 0.5f) ? a : best;
        idxT[tid] = best;
    }
}

// ---------------- qh GEMM: qh = relu(q @ Wq + bq), f16 out. 128 tiles of M=32 x N=128 ----------------
__global__ __launch_bounds__(256) void qh_gemm(
    const float* __restrict__ q,
    const float* __restrict__ bq,
    const char*  __restrict__ ws,
    char* __restrict__ wsout)
{
    const int tid = threadIdx.x, lane = tid & 63, w = tid >> 6;
    const int l15 = lane & 15, l4 = lane >> 4;
    const int bx  = blockIdx.x;              // 0..127
    const int r0  = (bx >> 1) * 32;
    const int nh  = bx & 1;
    const HALF* WqP = (const HALF*)(ws + WS_WQP);
    HALF* qh = (HALF*)(wsout + WS_QH);

    f32x4 acc[2][2];
    #pragma unroll
    for (int mt = 0; mt < 2; ++mt)
        #pragma unroll
        for (int nt = 0; nt < 2; ++nt) acc[mt][nt] = (f32x4)0.0f;

    #pragma unroll 2
    for (int kk = 0; kk < 8; ++kk) {
        half8 afr[2];
        #pragma unroll
        for (int mt = 0; mt < 2; ++mt) {
            const float* ap = &q[(size_t)(r0 + mt * 16 + l15) * EDIM + kk * 32 + l4 * 8];
            const float4 a0 = *reinterpret_cast<const float4*>(ap);
            const float4 a1 = *reinterpret_cast<const float4*>(ap + 4);
            half8 h;
            h[0] = (HALF)a0.x; h[1] = (HALF)a0.y; h[2] = (HALF)a0.z; h[3] = (HALF)a0.w;
            h[4] = (HALF)a1.x; h[5] = (HALF)a1.y; h[6] = (HALF)a1.z; h[7] = (HALF)a1.w;
            afr[mt] = h;
        }
        #pragma unroll
        for (int nt = 0; nt < 2; ++nt) {
            const int ntile = nh * 8 + w * 2 + nt;
            const half8 bfr = *reinterpret_cast<const half8*>(
                WqP + ((size_t)(ntile * 8 + kk) * 64 + lane) * 8);
            #pragma unroll
            for (int mt = 0; mt < 2; ++mt)
                acc[mt][nt] = __builtin_amdgcn_mfma_f32_16x16x32_f16(afr[mt], bfr, acc[mt][nt], 0, 0, 0);
        }
    }

    #pragma unroll
    for (int nt = 0; nt < 2; ++nt) {
        const int col = (nh * 8 + w * 2 + nt) * 16 + l15;
        const float bqa = bq[col];
        #pragma unroll
        for (int mt = 0; mt < 2; ++mt)
            #pragma unroll
            for (int r = 0; r < 4; ++r) {
                const int row = l4 * 4 + r;
                qh[(size_t)(r0 + mt * 16 + row) * EDIM + col] =
                    (HALF)fmaxf(acc[mt][nt][r] + bqa, 0.0f);
            }
    }
}

// ---------------- fused enc+attention: 2 (b,n)/block, 16 waves, K/V wave-split ----------------
// s_A[g] granule layout (per bidx g): granule(row=kk*4+mt, fl) at (row*64 + (fl^kk))*8 halves;
// holds enc[t = mt*16 + (fl&15)][e = kk*32 + (fl>>4)*8 + j].
// Wave w: kv = w>>3 (0 -> kh, 1 -> vh), hh = w&7 (head), both g.
__global__ __launch_bounds__(1024, 4) void attn2(
    const float* __restrict__ kin,
    const float* __restrict__ bk,
    const float* __restrict__ bv,
    const char*  __restrict__ ws,
    char* __restrict__ wsout)
{
    const int tid  = threadIdx.x;
    const int lane = tid & 63;
    const int w    = tid >> 6;          // 0..15
    const int kv   = w >> 3;            // 0 = K-wave, 1 = V-wave
    const int hh   = w & 7;             // head
    const int l15  = lane & 15;
    const int l4   = lane >> 4;
    const int bidx0 = blockIdx.x * 2;

    const HALF* WkP  = (const HALF*)(ws + WS_WKP);
    const HALF* WvP  = (const HALF*)(ws + WS_WVP);
    const HALF* PEH  = (const HALF*)(ws + WS_PEH);
    const HALF* WET  = (const HALF*)(ws + WS_WET);
    const HALF* qh   = (const HALF*)(ws + WS_QH);
    const int*  idxT = (const int*)(ws + WS_IDX);
    HALF* O = (HALF*)(wsout + WS_QH);   // overwrite own 2 qh rows at the end (safe per-row)

    __shared__ __align__(16) HALF  s_A[2 * 16384];   // 64 KB swizzled enc frags, per g
    __shared__ __align__(16) HALF  s_ng[2 * 2560];   // 10 KB neighT f16 [g][64][40]; reused as s_o
    __shared__ float s_att[NV][2][64];               // [head][g][t]
    float* s_o = (float*)s_ng;                       // 2 x 256 f32 (reused after enc)

    // ---- prefetch per-wave constants (hide under gather) ----
    float qv[2][2], bb[2];
    #pragma unroll
    for (int nt = 0; nt < 2; ++nt) {
        const int col = hh * 32 + nt * 16 + l15;
        qv[0][nt] = (float)qh[(size_t)bidx0 * EDIM + col];
        qv[1][nt] = (float)qh[(size_t)(bidx0 + 1) * EDIM + col];
        bb[nt] = kv ? bv[col] : bk[col];
    }

    // ---- gather neighbor actions -> f16 neighT [g][64][40], zero-padded k<32 ----
    #pragma unroll
    for (int i0 = 0; i0 < 2 * 64 * 32; i0 += 1024) {
        const int i = i0 + tid;
        const int g = i >> 11;
        const int t = (i >> 5) & 63;
        const int d = i & 31;
        float v = 0.0f;
        if (t < HIS && d < DKA) {
            const int bidx = bidx0 + g;
            v = kin[(((bidx >> 6) * HIS + t) * NA + idxT[(bidx & 63) * HIS + t]) * DKA + d];
        }
        s_ng[g * 2560 + t * 40 + d] = (HALF)v;
    }
    __syncthreads();

    // ---- enc via MFMA: wave w handles g = kv, e-tiles me = {2*hh, 2*hh+1} ----
    {
        const int g = kv;
        half8 aW[2];
        #pragma unroll
        for (int mi = 0; mi < 2; ++mi)
            aW[mi] = *reinterpret_cast<const half8*>(WET + ((size_t)(2 * hh + mi) * 64 + lane) * 8);

        f32x4 accE[2][4];
        #pragma unroll
        for (int mi = 0; mi < 2; ++mi)
            #pragma unroll
            for (int nt = 0; nt < 4; ++nt) accE[mi][nt] = (f32x4)0.0f;

        #pragma unroll
        for (int nt = 0; nt < 4; ++nt) {
            const half8 bN = *reinterpret_cast<const half8*>(
                &s_ng[g * 2560 + (nt * 16 + l15) * 40 + l4 * 8]);
            #pragma unroll
            for (int mi = 0; mi < 2; ++mi)
                accE[mi][nt] = __builtin_amdgcn_mfma_f32_16x16x32_f16(aW[mi], bN, accE[mi][nt], 0, 0, 0);
        }

        const int t_l = l4 & 1;
        #pragma unroll
        for (int mi = 0; mi < 2; ++mi) {
            const int me = 2 * hh + mi;
            const int e0 = me * 16 + l4 * 4;
            const int fg = mi * 2 + (l4 >> 1);
            #pragma unroll
            for (int nt = 0; nt < 4; ++nt) {
                const int t = nt * 16 + l15;
                half4 hv;
                if (t < HIS) {
                    const half4 pe = *reinterpret_cast<const half4*>(PEH + t * EDIM + e0);
                    hv[0] = (HALF)(gelu_exact(accE[mi][nt][0]) + (float)pe[0]);
                    hv[1] = (HALF)(gelu_exact(accE[mi][nt][1]) + (float)pe[1]);
                    hv[2] = (HALF)(gelu_exact(accE[mi][nt][2]) + (float)pe[2]);
                    hv[3] = (HALF)(gelu_exact(accE[mi][nt][3]) + (float)pe[3]);
                } else {
                    hv[0] = (HALF)0.0f; hv[1] = (HALF)0.0f;
                    hv[2] = (HALF)0.0f; hv[3] = (HALF)0.0f;
                }
                const int gran = (hh * 4 + nt) * 64 + ((fg * 16 + l15) ^ hh);
                *reinterpret_cast<half4*>(&s_A[g * 16384 + gran * 8 + t_l * 4]) = hv;
            }
        }
    }
    __syncthreads();

    // ---- K-loop: wave computes (kh or vh) for head hh, BOTH g; B-frags loaded once ----
    const HALF* BP = kv ? WvP : WkP;
    f32x4 acc[2][4][2];
    #pragma unroll
    for (int g = 0; g < 2; ++g)
        #pragma unroll
        for (int mt = 0; mt < 4; ++mt)
            #pragma unroll
            for (int nt = 0; nt < 2; ++nt) acc[g][mt][nt] = (f32x4)0.0f;

    #pragma unroll
    for (int kk = 0; kk < 8; ++kk) {
        half8 afr[2][4];
        #pragma unroll
        for (int g = 0; g < 2; ++g)
            #pragma unroll
            for (int mt = 0; mt < 4; ++mt)
                afr[g][mt] = *reinterpret_cast<const half8*>(
                    &s_A[g * 16384 + ((kk * 4 + mt) * 64 + (lane ^ kk)) * 8]);
        #pragma unroll
        for (int nt = 0; nt < 2; ++nt) {
            const half8 bfr = *reinterpret_cast<const half8*>(
                BP + (((hh * 2 + nt) * 8 + kk) * 64 + lane) * 8);
            #pragma unroll
            for (int g = 0; g < 2; ++g)
                #pragma unroll
                for (int mt = 0; mt < 4; ++mt)
                    acc[g][mt][nt] = __builtin_amdgcn_mfma_f32_16x16x32_f16(afr[g][mt], bfr, acc[g][mt][nt], 0, 0, 0);
        }
    }

    // ---- logits (K-waves only): relu(kh+bk) . qh, 16-lane reduce ----
    if (kv == 0) {
        #pragma unroll
        for (int g = 0; g < 2; ++g)
            #pragma unroll
            for (int mt = 0; mt < 4; ++mt)
                #pragma unroll
                for (int r = 0; r < 4; ++r) {
                    float p = qv[g][0] * fmaxf(acc[g][mt][0][r] + bb[0], 0.0f)
                            + qv[g][1] * fmaxf(acc[g][mt][1][r] + bb[1], 0.0f);
                    p += __shfl_xor(p, 1);
                    p += __shfl_xor(p, 2);
                    p += __shfl_xor(p, 4);
                    p += __shfl_xor(p, 8);
                    if (l15 == 0) s_att[hh][g][mt * 16 + l4 * 4 + r] = p * (1.0f / 3.0f);
                }
    }
    __syncthreads();

    // ---- softmax: wave w handles (head hh, g = kv), lane = t ----
    {
        const float val = (lane < HIS) ? s_att[hh][kv][lane] : -1e30f;
        float m = val;
        m = fmaxf(m, __shfl_xor(m, 1));
        m = fmaxf(m, __shfl_xor(m, 2));
        m = fmaxf(m, __shfl_xor(m, 4));
        m = fmaxf(m, __shfl_xor(m, 8));
        m = fmaxf(m, __shfl_xor(m, 16));
        m = fmaxf(m, __shfl_xor(m, 32));
        const float e = (lane < HIS) ? __expf(val - m) : 0.0f;
        float s = e;
        s += __shfl_xor(s, 1);
        s += __shfl_xor(s, 2);
        s += __shfl_xor(s, 4);
        s += __shfl_xor(s, 8);
        s += __shfl_xor(s, 16);
        s += __shfl_xor(s, 32);
        s_att[hh][kv][lane] = e * __builtin_amdgcn_rcpf(s);
    }
    __syncthreads();

    // ---- PV (V-waves only): both g; s_o reuses s_ng (enc reads long done) ----
    if (kv == 1) {
        #pragma unroll
        for (int g = 0; g < 2; ++g) {
            float o0 = 0.f, o1 = 0.f;
            #pragma unroll
            for (int mt = 0; mt < 4; ++mt)
                #pragma unroll
                for (int r = 0; r < 4; ++r) {
                    const int t = mt * 16 + l4 * 4 + r;
                    const float a = s_att[hh][g][t];
                    o0 += a * fmaxf(acc[g][mt][0][r] + bb[0], 0.0f);
                    o1 += a * fmaxf(acc[g][mt][1][r] + bb[1], 0.0f);
                }
            o0 += __shfl_xor(o0, 16); o1 += __shfl_xor(o1, 16);
            o0 += __shfl_xor(o0, 32); o1 += __shfl_xor(o1, 32);
            if (lane < 16) {
                s_o[g * 256 + hh * 32 +  0 + l15] = o0;
                s_o[g * 256 + hh * 32 + 16 + l15] = o1;
            }
        }
    }
    __syncthreads();

    // ---- write O rows (f16) for out_gemm ----
    if (tid < 512) {
        const int g = tid >> 8;
        const int c = tid & 255;
        O[(size_t)(bidx0 + g) * EDIM + c] = (HALF)s_o[g * 256 + c];
    }
}

// ---------------- out GEMM: out = relu(O @ Wout + bout), 128 tiles of M=32 x N=128 ----------------
__global__ __launch_bounds__(256) void out_gemm(
    const float* __restrict__ bout,
    const char*  __restrict__ ws,
    float* __restrict__ out)
{
    const int tid = threadIdx.x, lane = tid & 63, w = tid >> 6;
    const int l15 = lane & 15, l4 = lane >> 4;
    const int bx  = blockIdx.x;          // 0..127
    const int r0  = (bx >> 1) * 32;
    const int nh  = bx & 1;
    const HALF* WoP = (const HALF*)(ws + WS_WOP);
    const HALF* O   = (const HALF*)(ws + WS_QH);

    f32x4 acc[2][2];
    #pragma unroll
    for (int mt = 0; mt < 2; ++mt)
        #pragma unroll
        for (int nt = 0; nt < 2; ++nt) acc[mt][nt] = (f32x4)0.0f;

    #pragma unroll 2
    for (int kk = 0; kk < 8; ++kk) {
        half8 afr[2];
        #pragma unroll
        for (int mt = 0; mt < 2; ++mt)
            afr[mt] = *reinterpret_cast<const half8*>(
                &O[(size_t)(r0 + mt * 16 + l15) * EDIM + kk * 32 + l4 * 8]);
        #pragma unroll
        for (int nt = 0; nt < 2; ++nt) {
            const int ntile = nh * 8 + w * 2 + nt;
            const half8 bfr = *reinterpret_cast<const half8*>(
                WoP + ((size_t)(ntile * 8 + kk) * 64 + lane) * 8);
            #pragma unroll
            for (int mt = 0; mt < 2; ++mt)
                acc[mt][nt] = __builtin_amdgcn_mfma_f32_16x16x32_f16(afr[mt], bfr, acc[mt][nt], 0, 0, 0);
        }
    }

    #pragma unroll
    for (int nt = 0; nt < 2; ++nt) {
        const int col = (nh * 8 + w * 2 + nt) * 16 + l15;
        const float boa = bout[col];
        #pragma unroll
        for (int mt = 0; mt < 2; ++mt)
            #pragma unroll
            for (int r = 0; r < 4; ++r) {
                const int row = l4 * 4 + r;
                out[(size_t)(r0 + mt * 16 + row) * EDIM + col] =
                    fmaxf(acc[mt][nt][r] + boa, 0.0f);
            }
    }
}

// ---------------- fallback (ws too small; f32 path) ----------------
__global__ __launch_bounds__(256) void mha_fallback(
    const float* __restrict__ q,
    const float* __restrict__ kin,
    const float* __restrict__ adjs,
    const float* __restrict__ Wq, const float* __restrict__ bq,
    const float* __restrict__ Wk, const float* __restrict__ bk,
    const float* __restrict__ Wv, const float* __restrict__ bv,
    const float* __restrict__ Wout, const float* __restrict__ bout,
    const float* __restrict__ Wenc,
    float* __restrict__ out)
{
    const int tid  = threadIdx.x;
    const int bidx = blockIdx.x;
    const int b = bidx >> 6;
    const int n = bidx & 63;

    __shared__ __align__(16) float s_q[EDIM];
    __shared__ __align__(16) float s_qh[EDIM];
    __shared__ __align__(16) float s_neigh[HIS][12];
    __shared__ __align__(16) float s_enc[HIS * EDIM];
    __shared__ float s_att[NV][66];
    __shared__ __align__(16) float s_opart[4][EDIM];
    __shared__ __align__(16) float s_o[EDIM];
    __shared__ int s_idx[HIS];

    s_q[tid] = q[bidx * EDIM + tid];
    if (tid < HIS) {
        const float* row = adjs + (n * HIS + tid) * NA;
        int best = 0;
        #pragma unroll
        for (int a = 0; a < NA; ++a) best = (row[a] > 0.5f) ? a : best;
        s_idx[tid] = best;
    }
    __syncthreads();

    for (int i = tid; i < HIS * 12; i += 256) {
        const int t = i / 12;
        const int d = i - t * 12;
        float val = 0.0f;
        if (d < DKA) val = kin[((b * HIS + t) * NA + s_idx[t]) * DKA + d];
        s_neigh[t][d] = val;
    }
    __syncthreads();

    {
        const int e = tid;
        float acc = bq[e];
        #pragma unroll 4
        for (int d0 = 0; d0 < EDIM; d0 += 4) {
            const float4 qv = *reinterpret_cast<const float4*>(&s_q[d0]);
            acc += qv.x * Wq[(d0 + 0) * EDIM + e];
            acc += qv.y * Wq[(d0 + 1) * EDIM + e];
            acc += qv.z * Wq[(d0 + 2) * EDIM + e];
            acc += qv.w * Wq[(d0 + 3) * EDIM + e];
        }
        s_qh[e] = fmaxf(acc, 0.0f);

        float we[12];
        #pragma unroll
        for (int j = 0; j < 12; ++j) we[j] = (j < DKA) ? Wenc[j * EDIM + e] : 0.0f;
        const float dt = expf(-(float)(e & ~1) * (9.210340371976184f / 256.0f));
        for (int t = 0; t < HIS; ++t) {
            const float4 n0 = *reinterpret_cast<const float4*>(&s_neigh[t][0]);
            const float4 n1 = *reinterpret_cast<const float4*>(&s_neigh[t][4]);
            const float4 n2 = *reinterpret_cast<const float4*>(&s_neigh[t][8]);
            float x = n0.x*we[0] + n0.y*we[1] + n0.z*we[2] + n0.w*we[3]
                    + n1.x*we[4] + n1.y*we[5] + n1.z*we[6] + n1.w*we[7]
                    + n2.x*we[8];
            x = 0.5f * x * (1.0f + erff(x * 0.70710678118654752f));
            const float arg = (float)t * dt;
            const float pe = (e & 1) ? cosf(arg) : sinf(arg);
            s_enc[t * EDIM + e] = x + pe;
        }
    }
    __syncthreads();

    const int g = tid & 63;
    const int h = tid >> 6;
    const int tbase  = (h == 0) ? 0 : (h == 1) ? 13 : (h == 2) ? 25 : 37;
    const int tcount = (h == 1 || h == 2) ? 12 : 13;
    const int v = g >> 3;

    {
        float4 kacc[13];
        const float4 bkv = *reinterpret_cast<const float4*>(&bk[4 * g]);
        #pragma unroll
        for (int tt = 0; tt < 13; ++tt) kacc[tt] = bkv;
        #pragma unroll 2
        for (int d0 = 0; d0 < EDIM; d0 += 4) {
            const float4 w0 = *reinterpret_cast<const float4*>(&Wk[(d0 + 0) * EDIM + 4 * g]);
            const float4 w1 = *reinterpret_cast<const float4*>(&Wk[(d0 + 1) * EDIM + 4 * g]);
            const float4 w2 = *reinterpret_cast<const float4*>(&Wk[(d0 + 2) * EDIM + 4 * g]);
            const float4 w3 = *reinterpret_cast<const float4*>(&Wk[(d0 + 3) * EDIM + 4 * g]);
            #pragma unroll
            for (int tt = 0; tt < 13; ++tt) {
                const float4 ev = *reinterpret_cast<const float4*>(&s_enc[(tbase + tt) * EDIM + d0]);
                kacc[tt].x += ev.x * w0.x + ev.y * w1.x + ev.z * w2.x + ev.w * w3.x;
                kacc[tt].y += ev.x * w0.y + ev.y * w1.y + ev.z * w2.y + ev.w * w3.y;
                kacc[tt].z += ev.x * w0.z + ev.y * w1.z + ev.z * w2.z + ev.w * w3.z;
                kacc[tt].w += ev.x * w0.w + ev.y * w1.w + ev.z * w2.w + ev.w * w3.w;
            }
        }
        const float4 qv = *reinterpret_cast<const float4*>(&s_qh[4 * g]);
        #pragma unroll
        for (int tt = 0; tt < 13; ++tt) {
            float p = qv.x * fmaxf(kacc[tt].x, 0.0f)
                    + qv.y * fmaxf(kacc[tt].y, 0.0f)
                    + qv.z * fmaxf(kacc[tt].z, 0.0f)
                    + qv.w * fmaxf(kacc[tt].w, 0.0f);
            p += __shfl_xor(p, 1);
            p += __shfl_xor(p, 2);
            p += __shfl_xor(p, 4);
            if ((g & 7) == 0) s_att[v][tbase + tt] = p * (1.0f / 3.0f);
        }
    }
    __syncthreads();

    if (tid < NV) {
        float m = -1e30f;
        for (int t = 0; t < HIS; ++t) m = fmaxf(m, s_att[tid][t]);
        float ssum = 0.0f;
        for (int t = 0; t < HIS; ++t) {
            const float ex = expf(s_att[tid][t] - m);
            s_att[tid][t] = ex;
            ssum += ex;
        }
        const float inv = 1.0f / ssum;
        for (int t = 0; t < HIS; ++t) s_att[tid][t] *= inv;
    }
    __syncthreads();

    {
        float4 vacc[13];
        const float4 bvv = *reinterpret_cast<const float4*>(&bv[4 * g]);
        #pragma unroll
        for (int tt = 0; tt < 13; ++tt) vacc[tt] = bvv;
        #pragma unroll 2
        for (int d0 = 0; d0 < EDIM; d0 += 4) {
            const float4 w0 = *reinterpret_cast<const float4*>(&Wv[(d0 + 0) * EDIM + 4 * g]);
            const float4 w1 = *reinterpret_cast<const float4*>(&Wv[(d0 + 1) * EDIM + 4 * g]);
            const float4 w2 = *reinterpret_cast<const float4*>(&Wv[(d0 + 2) * EDIM + 4 * g]);
            const float4 w3 = *reinterpret_cast<const float4*>(&Wv[(d0 + 3) * EDIM + 4 * g]);
            #pragma unroll
            for (int tt = 0; tt < 13; ++tt) {
                const float4 ev = *reinterpret_cast<const float4*>(&s_enc[(tbase + tt) * EDIM + d0]);
                vacc[tt].x += ev.x * w0.x + ev.y * w1.x + ev.z * w2.x + ev.w * w3.x;
                vacc[tt].y += ev.x * w0.y + ev.y * w1.y + ev.z * w2.y + ev.w * w3.y;
                vacc[tt].z += ev.x * w0.z + ev.y * w1.z + ev.z * w2.z + ev.w * w3.z;
                vacc[tt].w += ev.x * w0.w + ev.y * w1.w + ev.z * w2.w + ev.w * w3.w;
            }
        }
        float4 po = make_float4(0.0f, 0.0f, 0.0f, 0.0f);
        #pragma unroll
        for (int tt = 0; tt < 13; ++tt) {
            if (tt < tcount) {
                const float a = s_att[v][tbase + tt];
                po.x += a * fmaxf(vacc[tt].x, 0.0f);
                po.y += a * fmaxf(vacc[tt].y, 0.0f);
                po.z += a * fmaxf(vacc[tt].z, 0.0f);
                po.w += a * fmaxf(vacc[tt].w, 0.0f);
            }
        }
        *reinterpret_cast<float4*>(&s_opart[h][4 * g]) = po;
    }
    __syncthreads();

    s_o[tid] = s_opart[0][tid] + s_opart[1][tid] + s_opart[2][tid] + s_opart[3][tid];
    __syncthreads();

    {
        const int e = tid;
        float acc = bout[e];
        #pragma unroll 4
        for (int d0 = 0; d0 < EDIM; d0 += 4) {
            const float4 ov = *reinterpret_cast<const float4*>(&s_o[d0]);
            acc += ov.x * Wout[(d0 + 0) * EDIM + e];
            acc += ov.y * Wout[(d0 + 1) * EDIM + e];
            acc += ov.z * Wout[(d0 + 2) * EDIM + e];
            acc += ov.w * Wout[(d0 + 3) * EDIM + e];
        }
        out[bidx * EDIM + e] = fmaxf(acc, 0.0f);
    }
}

extern "C" void kernel_launch(void* const* d_in, const int* in_sizes, int n_in,
                              void* d_out, int out_size, void* d_ws, size_t ws_size,
                              hipStream_t stream) {
    const float* q    = (const float*)d_in[0];
    const float* kin  = (const float*)d_in[1];
    const float* adjs = (const float*)d_in[2];
    const float* Wq   = (const float*)d_in[3];
    const float* bq   = (const float*)d_in[4];
    const float* Wk   = (const float*)d_in[5];
    const float* bk   = (const float*)d_in[6];
    const float* Wv   = (const float*)d_in[7];
    const float* bv   = (const float*)d_in[8];
    const float* Wout = (const float*)d_in[9];
    const float* bout = (const float*)d_in[10];
    const float* Wenc = (const float*)d_in[11];
    float* out = (float*)d_out;
    char* ws = (char*)d_ws;

    if (ws_size >= WS_NEED) {
        hipLaunchKernelGGL(pack_setup, dim3(256), dim3(256), 0, stream,
                           Wk, Wv, Wq, Wout, adjs, Wenc, ws);
        hipLaunchKernelGGL(qh_gemm, dim3(128), dim3(256), 0, stream,
                           q, bq, ws, ws);
        hipLaunchKernelGGL(attn2, dim3(NB * NA / 2), dim3(1024), 0, stream,
                           kin, bk, bv, ws, ws);
        hipLaunchKernelGGL(out_gemm, dim3(128), dim3(256), 0, stream,
                           bout, ws, out);
    } else {
        hipLaunchKernelGGL(mha_fallback, dim3(NB * NA), dim3(256), 0, stream,
                           q, kin, adjs, Wq, bq, Wk, bk, Wv, bv, Wout, bout, Wenc, out);
    }
}